// Round 7
// baseline (542.299 us; speedup 1.0000x reference)
//
#include <hip/hip_runtime.h>
#include <hip/hip_bf16.h>
#include <cmath>
#include <cstdint>

// AttentionPoolingAggregator — MI355X round 11
//  * gemm_persist: __syncthreads() (= s_waitcnt vmcnt(0) lgkmcnt(0); s_barrier)
//    replaced by lgkmcnt(0)-only + raw s_barrier. The full drain was killing
//    every pipelining attempt (rounds 6-10 all ~122us): prefetch loads AND the
//    40 proj/xbf stores were forcibly retired at every tile barrier, fully
//    serializing memory against compute with 1 block/CU. LDS dbuf correctness
//    needs only lgkm; loads are consumed via compiler counted-vmcnt register
//    waits; stores retire by kernel end. Stores now issued AFTER next-next
//    tile loads (FIFO -> load-wait leaves stores in flight).
//  * edge_flash / prep / scan / fill unchanged.

#define H 256

typedef __attribute__((ext_vector_type(8))) short bfrag;  // 8 bf16 (4 VGPRs)
typedef __attribute__((ext_vector_type(4))) float ffrag;  // 4 fp32 acc

__device__ __forceinline__ ushort f2bf(float f) {  // fp32 -> bf16 RNE
  uint u = __float_as_uint(f);
  uint r = u + 0x7FFFu + ((u >> 16) & 1u);
  return (ushort)(r >> 16);
}
__device__ __forceinline__ float bf2f(ushort h) {
  return __uint_as_float((uint)h << 16);
}

// ---------------- prep: wsplit(W_news) | wsplit(W_company) | count histogram ----------------
__global__ void prep_kernel(const float* __restrict__ Wn, const float* __restrict__ Wc,
                            ushort* __restrict__ WnHi, ushort* __restrict__ WnLo,
                            ushort* __restrict__ WcHi, ushort* __restrict__ WcLo,
                            const int* __restrict__ dst, int* __restrict__ counts, int E) {
  const int b = blockIdx.x, tid = threadIdx.x;
  if (b < 256) {
    int i = b * 256 + tid;
    float w = Wn[i];
    ushort h = f2bf(w);
    WnHi[i] = h;
    WnLo[i] = f2bf(w - bf2f(h));
  } else if (b < 512) {
    int i = (b - 256) * 256 + tid;
    float w = Wc[i];
    ushort h = f2bf(w);
    WcHi[i] = h;
    WcLo[i] = f2bf(w - bf2f(h));
  } else {
    int e = (b - 512) * 256 + tid;
    if (e < E) atomicAdd(&counts[dst[e]], 1);
  }
}

// single-block scan over C counts -> exclusive offsets[0..C], cursor copy
__global__ void scan_kernel(const int* __restrict__ counts, int* __restrict__ offsets,
                            int* __restrict__ cursor, int C) {
  __shared__ int wsum[16];
  int tid = threadIdx.x;
  int lane = tid & 63, wid = tid >> 6;
  int base = 0;
  for (int start = 0; start < C; start += 1024) {
    int idx = start + tid;
    int val = (idx < C) ? counts[idx] : 0;
    int x = val;
#pragma unroll
    for (int off = 1; off < 64; off <<= 1) {
      int y = __shfl_up(x, off);
      if (lane >= off) x += y;
    }
    if (lane == 63) wsum[wid] = x;
    __syncthreads();
    int add = base;
    for (int w = 0; w < wid; ++w) add += wsum[w];
    if (idx < C) {
      int excl = add + x - val;
      offsets[idx] = excl;
      cursor[idx]  = excl;
    }
    int tot = 0;
#pragma unroll
    for (int w = 0; w < 16; ++w) tot += wsum[w];
    __syncthreads();
    base += tot;
  }
  if (tid == 0) offsets[C] = base;
}

__global__ void fill_kernel(const int* __restrict__ src, const int* __restrict__ dst,
                            int* __restrict__ cursor, int* __restrict__ srcs_sorted, int E) {
  int e = blockIdx.x * blockDim.x + threadIdx.x;
  if (e < E) {
    int d = dst[e];
    int pos = atomicAdd(&cursor[d], 1);
    srcs_sorted[pos] = src[e];
  }
}

// ---------------- persistent-W MFMA GEMM, lgkm-only barrier ----------------
__global__ __launch_bounds__(512, 2) void gemm_persist(
    const float* __restrict__ Xc, const ushort* __restrict__ WcHi,
    const ushort* __restrict__ WcLo, ushort* __restrict__ cproj, int MC, int GC,
    const float* __restrict__ Xn, const ushort* __restrict__ WnHi,
    const ushort* __restrict__ WnLo, ushort* __restrict__ nproj,
    ushort* __restrict__ nxbf, int MN) {
  constexpr int PITCH = 264;              // ushorts per LDS row (528B = 33*16B)
  __shared__ ushort Xs[2][64 * PITCH];    // 2 x 33.8 KB double buffer
  const int tid = threadIdx.x;
  const int wv = tid >> 6, lane = tid & 63;
  const int q = lane >> 4, nidx = lane & 15;
  const int GN = gridDim.x - GC;

  const float* X; const ushort *Whi, *Wlo; ushort *proj, *xb; int M, nb, lb;
  if ((int)blockIdx.x < GC) {
    X = Xc; Whi = WcHi; Wlo = WcLo; proj = cproj; xb = nullptr; M = MC;
    nb = GC; lb = blockIdx.x;
  } else {
    X = Xn; Whi = WnHi; Wlo = WnLo; proj = nproj; xb = nxbf; M = MN;
    nb = GN; lb = blockIdx.x - GC;
  }
  const int nt = (M + 63) >> 6;                       // tiles for this side
  const int qt = nt / nb, rt = nt % nb;
  const int first = lb * qt + (lb < rt ? lb : rt);    // contiguous chunk
  const int cnt = qt + (lb < rt ? 1 : 0);
  if (cnt <= 0) return;

  // ---- persistent W fragments: this wave's 32 output cols, hi+lo, all 8 k-slices ----
  bfrag bhi[8][2], blo[8][2];  // 32 bfrags = 128 regs, live for whole kernel
#pragma unroll
  for (int ks = 0; ks < 8; ++ks)
#pragma unroll
    for (int tt = 0; tt < 2; ++tt) {
      const size_t off = (size_t)(wv * 32 + tt * 16 + nidx) * H + ks * 32 + q * 8;
      bhi[ks][tt] = *(const bfrag*)(Whi + off);
      blo[ks][tt] = *(const bfrag*)(Wlo + off);
    }

  float4 xr[8];  // staging registers: 64x256 fp32 tile / 512 thr = 8 float4 each
  auto load8 = [&](int tile) {
#pragma unroll
    for (int j = 0; j < 8; ++j) {
      const int flat = j * 2048 + tid * 4;            // fully coalesced
      int gr = tile * 64 + (flat >> 8);
      if (gr >= M) gr = M - 1;                        // company tail: dup reads
      xr[j] = *(const float4*)(X + (size_t)gr * H + (flat & 255));
    }
  };
  auto writebuf = [&](int p, int tile) {
#pragma unroll
    for (int j = 0; j < 8; ++j) {
      const int flat = j * 2048 + tid * 4;
      const int r = flat >> 8, k = flat & 255;
      ushort4 b4;
      b4.x = f2bf(xr[j].x); b4.y = f2bf(xr[j].y);
      b4.z = f2bf(xr[j].z); b4.w = f2bf(xr[j].w);
      *(ushort4*)&Xs[p][r * PITCH + k] = b4;
      if (xb) {
        const int gr = tile * 64 + r;                 // news: full tiles, no clamp
        *(ushort4*)(xb + (size_t)gr * H + k) = b4;
      }
    }
  };

  // prologue: stage tile 0; issue loads for tile 1 (consumed NEXT iteration)
  load8(first);
  writebuf(0, first);
  if (cnt > 1) load8(first + 1);
  int p = 0;
  for (int t = 0; t < cnt; ++t) {
    // lgkm-only barrier: ds_writes of buf[p] visible; global loads/stores
    // stay in flight across the barrier (T4: never vmcnt(0) in main loop).
    asm volatile("s_waitcnt lgkmcnt(0)" ::: "memory");
    __builtin_amdgcn_sched_barrier(0);
    __builtin_amdgcn_s_barrier();
    __builtin_amdgcn_sched_barrier(0);
    const int tile = first + t;

    ffrag acc[4][2];
#pragma unroll
    for (int i = 0; i < 4; ++i) { acc[i][0] = (ffrag)(0.f); acc[i][1] = (ffrag)(0.f); }
#pragma unroll
    for (int ks = 0; ks < 8; ++ks) {
      bfrag a[4];
#pragma unroll
      for (int i = 0; i < 4; ++i)
        a[i] = *(const bfrag*)&Xs[p][(16 * i + nidx) * PITCH + ks * 32 + q * 8];
#pragma unroll
      for (int i = 0; i < 4; ++i)
#pragma unroll
        for (int tt = 0; tt < 2; ++tt) {
          acc[i][tt] = __builtin_amdgcn_mfma_f32_16x16x32_bf16(a[i], bhi[ks][tt], acc[i][tt], 0, 0, 0);
          acc[i][tt] = __builtin_amdgcn_mfma_f32_16x16x32_bf16(a[i], blo[ks][tt], acc[i][tt], 0, 0, 0);
        }
    }

    // stage t+1 (counted vmcnt wait on xr only), then issue t+2 loads, THEN
    // the proj stores — loads precede stores in the vmcnt FIFO, so next
    // iteration's xr wait leaves these stores in flight.
    if (t + 1 < cnt) writebuf(p ^ 1, tile + 1);
    if (t + 2 < cnt) load8(tile + 2);

    const int row0 = tile * 64;
#pragma unroll
    for (int i = 0; i < 4; ++i)
#pragma unroll
      for (int r = 0; r < 4; ++r) {
        const int grow = row0 + 16 * i + q * 4 + r;
        if (grow < M) {
#pragma unroll
          for (int tt = 0; tt < 2; ++tt)
            proj[(size_t)grow * H + wv * 32 + tt * 16 + nidx] = f2bf(acc[i][tt][r]);
        }
      }
    p ^= 1;
  }
}

// ---------------- split-wave flash edge kernel (round-7 version) ----------------
// 4 instrs (2 trans), no IEEE div:  tanh(x) = 1 - 2*rcp(exp2(2x*log2e)+1)
__device__ __forceinline__ float fast_tanh(float x) {
  float e = __builtin_amdgcn_exp2f(x * 2.8853900817779268f);  // e^{2x}
  float t = __builtin_amdgcn_rcpf(e + 1.f);
  return __builtin_fmaf(-2.f, t, 1.f);
}

__global__ __launch_bounds__(256) void edge_flash_kernel(
    const ushort* __restrict__ news_projbf, const ushort* __restrict__ company_projbf,
    const float* __restrict__ v, const int* __restrict__ offsets,
    const int* __restrict__ srcs, const ushort* __restrict__ news_xbf,
    float* __restrict__ out) {
  const int c = blockIdx.x;
  const int tid = threadIdx.x;
  const int sl = tid & 31;   // sub-lane within half-wave (owns dims sl*8..sl*8+7)
  const int hw = tid >> 5;   // half-wave id 0..7 (owns edges beg+hw, +8, +16, ...)
  __shared__ float cp[H];
  __shared__ float mW[8], lW[8];
  __shared__ float OW[8][H];  // 8 KB
  cp[tid] = bf2f(company_projbf[(size_t)c * H + tid]);
  __syncthreads();
  const float4 va = *(const float4*)(v + sl * 8);
  const float4 vb = *(const float4*)(v + sl * 8 + 4);
  const float4 ca = *(const float4*)&cp[sl * 8];
  const float4 cb = *(const float4*)&cp[sl * 8 + 4];
  const float vv[8] = {va.x, va.y, va.z, va.w, vb.x, vb.y, vb.z, vb.w};
  const float cq[8] = {ca.x, ca.y, ca.z, ca.w, cb.x, cb.y, cb.z, cb.w};
  const int beg = offsets[c], end = offsets[c + 1];

  float m = -INFINITY, l = 0.f;
  float O[8] = {0.f, 0.f, 0.f, 0.f, 0.f, 0.f, 0.f, 0.f};

  int i = beg + hw;
  if (i < end) {
    int s = srcs[i];
    bfrag pr = *(const bfrag*)(news_projbf + (size_t)s * H + sl * 8);
    bfrag xr = *(const bfrag*)(news_xbf + (size_t)s * H + sl * 8);
    for (;;) {
      const int inext = i + 8;
      const bool more = (inext < end);  // half-wave uniform
      bfrag prn, xrn;
      if (more) {  // prefetch next edge while computing current
        int sn = srcs[inext];
        prn = *(const bfrag*)(news_projbf + (size_t)sn * H + sl * 8);
        xrn = *(const bfrag*)(news_xbf + (size_t)sn * H + sl * 8);
      }
      float r = 0.f;
#pragma unroll
      for (int j = 0; j < 8; ++j)
        r += fast_tanh(bf2f((ushort)pr[j]) + cq[j]) * vv[j];
#pragma unroll
      for (int off = 16; off > 0; off >>= 1) r += __shfl_xor(r, off);
      const float mnew = fmaxf(m, r);
      const float alpha = __expf(m - mnew);  // first iter: exp(-inf)=0
      const float pa = __expf(r - mnew);
      l = l * alpha + pa;
#pragma unroll
      for (int j = 0; j < 8; ++j)
        O[j] = O[j] * alpha + pa * bf2f((ushort)xr[j]);
      m = mnew;
      i = inext;
      if (!more) break;
      pr = prn; xr = xrn;
    }
  }

  // ---- merge 8 half-waves ----
  if (sl == 0) { mW[hw] = m; lW[hw] = l; }
  *(float4*)&OW[hw][sl * 8]     = make_float4(O[0], O[1], O[2], O[3]);
  *(float4*)&OW[hw][sl * 8 + 4] = make_float4(O[4], O[5], O[6], O[7]);
  __syncthreads();
  float mstar = -INFINITY;
#pragma unroll
  for (int w = 0; w < 8; ++w) mstar = fmaxf(mstar, mW[w]);
  float denom = 0.f, val = 0.f;
#pragma unroll
  for (int w = 0; w < 8; ++w) {
    const float sc = (lW[w] > 0.f) ? __expf(mW[w] - mstar) : 0.f;
    denom += lW[w] * sc;
    val += OW[w][tid] * sc;
  }
  out[(size_t)c * H + tid] = val / fmaxf(denom, 1e-9f);
}

// ---------------- launch ----------------
extern "C" void kernel_launch(void* const* d_in, const int* in_sizes, int n_in,
                              void* d_out, int out_size, void* d_ws, size_t ws_size,
                              hipStream_t stream) {
  const float* news_x    = (const float*)d_in[0];
  const float* company_x = (const float*)d_in[1];
  const float* W_news    = (const float*)d_in[2];
  const float* W_company = (const float*)d_in[3];
  const float* v         = (const float*)d_in[4];
  const int*   src       = (const int*)d_in[5];
  const int*   dst       = (const int*)d_in[6];
  const int N = in_sizes[0] / H;
  const int C = in_sizes[1] / H;
  const int E = in_sizes[5];
  float* out = (float*)d_out;

  char* p = (char*)d_ws;
  ushort* news_projbf    = (ushort*)p; p += (size_t)N * H * sizeof(ushort);
  ushort* news_xbf       = (ushort*)p; p += (size_t)N * H * sizeof(ushort);
  ushort* company_projbf = (ushort*)p; p += (size_t)C * H * sizeof(ushort);
  int*    srcs_sorted    = (int*)p;    p += (size_t)E * sizeof(int);
  ushort* Wn_hi          = (ushort*)p; p += (size_t)H * H * sizeof(ushort);
  ushort* Wn_lo          = (ushort*)p; p += (size_t)H * H * sizeof(ushort);
  ushort* Wc_hi          = (ushort*)p; p += (size_t)H * H * sizeof(ushort);
  ushort* Wc_lo          = (ushort*)p; p += (size_t)H * H * sizeof(ushort);
  int*    counts         = (int*)p;    p += (size_t)C * sizeof(int);
  int*    offsets        = (int*)p;    p += (size_t)(C + 1) * sizeof(int);
  int*    cursor         = (int*)p;    p += (size_t)C * sizeof(int);

  hipMemsetAsync(counts, 0, (size_t)C * sizeof(int), stream);
  prep_kernel<<<512 + (E + 255) / 256, 256, 0, stream>>>(
      W_news, W_company, Wn_hi, Wn_lo, Wc_hi, Wc_lo, dst, counts, E);
  scan_kernel<<<1, 1024, 0, stream>>>(counts, offsets, cursor, C);
  fill_kernel<<<(E + 255) / 256, 256, 0, stream>>>(src, dst, cursor, srcs_sorted, E);

  // 256 blocks = 1 persistent block/CU. company 157/12=13.1, news 3125/244=12.8.
  const int GC = 12, GN = 244;
  gemm_persist<<<GC + GN, 512, 0, stream>>>(
      company_x, Wc_hi, Wc_lo, company_projbf, C, GC,
      news_x, Wn_hi, Wn_lo, news_projbf, news_xbf, N);

  edge_flash_kernel<<<C, 256, 0, stream>>>(news_projbf, company_projbf, v, offsets,
                                           srcs_sorted, news_xbf, out);
}

// Round 8
// 533.377 us; speedup vs baseline: 1.0167x; 1.0167x over previous
//
#include <hip/hip_runtime.h>
#include <hip/hip_bf16.h>
#include <cmath>
#include <cstdint>

// AttentionPoolingAggregator — MI355X round 12
//  * gemm_persist restructured 8x32col -> 16x16col waves (1024-thr block,
//    launch_bounds(1024,1)). Round 8-11 all neutral because the kernel was
//    TLP-starved: 124 VGPR + 32 acc = 156/wave -> 2 waves/SIMD (512-reg pool),
//    lockstep barrier phases fully exposed. 16-col waves need W 64 + acc 16 +
//    stage 16 + a 16 ~= 112+addr <= 128 -> 4 waves/SIMD at 1 block/CU.
//    Same total MFMA work, same LDS, same single barrier per tile.
//  * Barrier back to plain __syncthreads (lgkm-only variant measured neutral).
//  * edge_flash / prep / scan / fill unchanged.

#define H 256

typedef __attribute__((ext_vector_type(8))) short bfrag;  // 8 bf16 (4 VGPRs)
typedef __attribute__((ext_vector_type(4))) float ffrag;  // 4 fp32 acc

__device__ __forceinline__ ushort f2bf(float f) {  // fp32 -> bf16 RNE
  uint u = __float_as_uint(f);
  uint r = u + 0x7FFFu + ((u >> 16) & 1u);
  return (ushort)(r >> 16);
}
__device__ __forceinline__ float bf2f(ushort h) {
  return __uint_as_float((uint)h << 16);
}

// ---------------- prep: wsplit(W_news) | wsplit(W_company) | count histogram ----------------
__global__ void prep_kernel(const float* __restrict__ Wn, const float* __restrict__ Wc,
                            ushort* __restrict__ WnHi, ushort* __restrict__ WnLo,
                            ushort* __restrict__ WcHi, ushort* __restrict__ WcLo,
                            const int* __restrict__ dst, int* __restrict__ counts, int E) {
  const int b = blockIdx.x, tid = threadIdx.x;
  if (b < 256) {
    int i = b * 256 + tid;
    float w = Wn[i];
    ushort h = f2bf(w);
    WnHi[i] = h;
    WnLo[i] = f2bf(w - bf2f(h));
  } else if (b < 512) {
    int i = (b - 256) * 256 + tid;
    float w = Wc[i];
    ushort h = f2bf(w);
    WcHi[i] = h;
    WcLo[i] = f2bf(w - bf2f(h));
  } else {
    int e = (b - 512) * 256 + tid;
    if (e < E) atomicAdd(&counts[dst[e]], 1);
  }
}

// single-block scan over C counts -> exclusive offsets[0..C], cursor copy
__global__ void scan_kernel(const int* __restrict__ counts, int* __restrict__ offsets,
                            int* __restrict__ cursor, int C) {
  __shared__ int wsum[16];
  int tid = threadIdx.x;
  int lane = tid & 63, wid = tid >> 6;
  int base = 0;
  for (int start = 0; start < C; start += 1024) {
    int idx = start + tid;
    int val = (idx < C) ? counts[idx] : 0;
    int x = val;
#pragma unroll
    for (int off = 1; off < 64; off <<= 1) {
      int y = __shfl_up(x, off);
      if (lane >= off) x += y;
    }
    if (lane == 63) wsum[wid] = x;
    __syncthreads();
    int add = base;
    for (int w = 0; w < wid; ++w) add += wsum[w];
    if (idx < C) {
      int excl = add + x - val;
      offsets[idx] = excl;
      cursor[idx]  = excl;
    }
    int tot = 0;
#pragma unroll
    for (int w = 0; w < 16; ++w) tot += wsum[w];
    __syncthreads();
    base += tot;
  }
  if (tid == 0) offsets[C] = base;
}

__global__ void fill_kernel(const int* __restrict__ src, const int* __restrict__ dst,
                            int* __restrict__ cursor, int* __restrict__ srcs_sorted, int E) {
  int e = blockIdx.x * blockDim.x + threadIdx.x;
  if (e < E) {
    int d = dst[e];
    int pos = atomicAdd(&cursor[d], 1);
    srcs_sorted[pos] = src[e];
  }
}

// ---------------- persistent-W MFMA GEMM: 16 waves x 16 cols, 4 waves/SIMD ----------------
__global__ __launch_bounds__(1024, 1) void gemm_persist(
    const float* __restrict__ Xc, const ushort* __restrict__ WcHi,
    const ushort* __restrict__ WcLo, ushort* __restrict__ cproj, int MC, int GC,
    const float* __restrict__ Xn, const ushort* __restrict__ WnHi,
    const ushort* __restrict__ WnLo, ushort* __restrict__ nproj,
    ushort* __restrict__ nxbf, int MN) {
  constexpr int PITCH = 264;              // ushorts per LDS row (528B = 33*16B)
  __shared__ ushort Xs[2][64 * PITCH];    // 2 x 33.8 KB double buffer
  const int tid = threadIdx.x;
  const int wv = tid >> 6, lane = tid & 63;   // wv in 0..15: owns cols wv*16..+15
  const int q = lane >> 4, nidx = lane & 15;
  const int GN = gridDim.x - GC;

  const float* X; const ushort *Whi, *Wlo; ushort *proj, *xb; int M, nb, lb;
  if ((int)blockIdx.x < GC) {
    X = Xc; Whi = WcHi; Wlo = WcLo; proj = cproj; xb = nullptr; M = MC;
    nb = GC; lb = blockIdx.x;
  } else {
    X = Xn; Whi = WnHi; Wlo = WnLo; proj = nproj; xb = nxbf; M = MN;
    nb = GN; lb = blockIdx.x - GC;
  }
  const int nt = (M + 63) >> 6;                       // tiles for this side
  const int qt = nt / nb, rt = nt % nb;
  const int first = lb * qt + (lb < rt ? lb : rt);    // contiguous chunk
  const int cnt = qt + (lb < rt ? 1 : 0);
  if (cnt <= 0) return;

  // ---- persistent W fragments: this wave's 16 output cols, hi+lo, 8 k-slices ----
  bfrag bhi[8], blo[8];  // 16 bfrags = 64 VGPRs
#pragma unroll
  for (int ks = 0; ks < 8; ++ks) {
    const size_t off = (size_t)(wv * 16 + nidx) * H + ks * 32 + q * 8;
    bhi[ks] = *(const bfrag*)(Whi + off);
    blo[ks] = *(const bfrag*)(Wlo + off);
  }

  float4 xr[4];  // staging: 64x256 fp32 tile / 1024 thr = 4 float4 each
  auto load4 = [&](int tile) {
#pragma unroll
    for (int j = 0; j < 4; ++j) {
      const int flat = j * 4096 + tid * 4;            // fully coalesced 16B/lane
      int gr = tile * 64 + (flat >> 8);
      if (gr >= M) gr = M - 1;                        // company tail: dup reads
      xr[j] = *(const float4*)(X + (size_t)gr * H + (flat & 255));
    }
  };
  auto writebuf = [&](int p, int tile) {
#pragma unroll
    for (int j = 0; j < 4; ++j) {
      const int flat = j * 4096 + tid * 4;
      const int r = flat >> 8, k = flat & 255;
      ushort4 b4;
      b4.x = f2bf(xr[j].x); b4.y = f2bf(xr[j].y);
      b4.z = f2bf(xr[j].z); b4.w = f2bf(xr[j].w);
      *(ushort4*)&Xs[p][r * PITCH + k] = b4;
      if (xb) {
        const int gr = tile * 64 + r;                 // news: full tiles, no clamp
        *(ushort4*)(xb + (size_t)gr * H + k) = b4;
      }
    }
  };

  // prologue: stage first tile into buffer 0
  load4(first);
  writebuf(0, first);
  int p = 0;
  for (int t = 0; t < cnt; ++t) {
    __syncthreads();                                  // buf[p] ready; buf[p^1] free
    const int tile = first + t;
    const bool more = (t + 1 < cnt);
    if (more) load4(tile + 1);                        // latency hidden by 4 waves/SIMD

    ffrag acc[4];
#pragma unroll
    for (int i = 0; i < 4; ++i) acc[i] = (ffrag)(0.f);
#pragma unroll
    for (int ks = 0; ks < 8; ++ks) {
      bfrag a[4];
#pragma unroll
      for (int i = 0; i < 4; ++i)
        a[i] = *(const bfrag*)&Xs[p][(16 * i + nidx) * PITCH + ks * 32 + q * 8];
#pragma unroll
      for (int i = 0; i < 4; ++i) {
        acc[i] = __builtin_amdgcn_mfma_f32_16x16x32_bf16(a[i], bhi[ks], acc[i], 0, 0, 0);
        acc[i] = __builtin_amdgcn_mfma_f32_16x16x32_bf16(a[i], blo[ks], acc[i], 0, 0, 0);
      }
    }

    const int row0 = tile * 64;
#pragma unroll
    for (int i = 0; i < 4; ++i)
#pragma unroll
      for (int r = 0; r < 4; ++r) {
        const int grow = row0 + 16 * i + q * 4 + r;
        if (grow < M)
          proj[(size_t)grow * H + wv * 16 + nidx] = f2bf(acc[i][r]);
      }

    if (more) writebuf(p ^ 1, tile + 1);              // write-late into free buffer
    p ^= 1;
  }
}

// ---------------- split-wave flash edge kernel ----------------
// 4 instrs (2 trans), no IEEE div:  tanh(x) = 1 - 2*rcp(exp2(2x*log2e)+1)
__device__ __forceinline__ float fast_tanh(float x) {
  float e = __builtin_amdgcn_exp2f(x * 2.8853900817779268f);  // e^{2x}
  float t = __builtin_amdgcn_rcpf(e + 1.f);
  return __builtin_fmaf(-2.f, t, 1.f);
}

__global__ __launch_bounds__(256) void edge_flash_kernel(
    const ushort* __restrict__ news_projbf, const ushort* __restrict__ company_projbf,
    const float* __restrict__ v, const int* __restrict__ offsets,
    const int* __restrict__ srcs, const ushort* __restrict__ news_xbf,
    float* __restrict__ out) {
  const int c = blockIdx.x;
  const int tid = threadIdx.x;
  const int sl = tid & 31;   // sub-lane within half-wave (owns dims sl*8..sl*8+7)
  const int hw = tid >> 5;   // half-wave id 0..7 (owns edges beg+hw, +8, +16, ...)
  __shared__ float cp[H];
  __shared__ float mW[8], lW[8];
  __shared__ float OW[8][H];  // 8 KB
  cp[tid] = bf2f(company_projbf[(size_t)c * H + tid]);
  __syncthreads();
  const float4 va = *(const float4*)(v + sl * 8);
  const float4 vb = *(const float4*)(v + sl * 8 + 4);
  const float4 ca = *(const float4*)&cp[sl * 8];
  const float4 cb = *(const float4*)&cp[sl * 8 + 4];
  const float vv[8] = {va.x, va.y, va.z, va.w, vb.x, vb.y, vb.z, vb.w};
  const float cq[8] = {ca.x, ca.y, ca.z, ca.w, cb.x, cb.y, cb.z, cb.w};
  const int beg = offsets[c], end = offsets[c + 1];

  float m = -INFINITY, l = 0.f;
  float O[8] = {0.f, 0.f, 0.f, 0.f, 0.f, 0.f, 0.f, 0.f};

  int i = beg + hw;
  if (i < end) {
    int s = srcs[i];
    bfrag pr = *(const bfrag*)(news_projbf + (size_t)s * H + sl * 8);
    bfrag xr = *(const bfrag*)(news_xbf + (size_t)s * H + sl * 8);
    for (;;) {
      const int inext = i + 8;
      const bool more = (inext < end);  // half-wave uniform
      bfrag prn, xrn;
      if (more) {  // prefetch next edge while computing current
        int sn = srcs[inext];
        prn = *(const bfrag*)(news_projbf + (size_t)sn * H + sl * 8);
        xrn = *(const bfrag*)(news_xbf + (size_t)sn * H + sl * 8);
      }
      float r = 0.f;
#pragma unroll
      for (int j = 0; j < 8; ++j)
        r += fast_tanh(bf2f((ushort)pr[j]) + cq[j]) * vv[j];
#pragma unroll
      for (int off = 16; off > 0; off >>= 1) r += __shfl_xor(r, off);
      const float mnew = fmaxf(m, r);
      const float alpha = __expf(m - mnew);  // first iter: exp(-inf)=0
      const float pa = __expf(r - mnew);
      l = l * alpha + pa;
#pragma unroll
      for (int j = 0; j < 8; ++j)
        O[j] = O[j] * alpha + pa * bf2f((ushort)xr[j]);
      m = mnew;
      i = inext;
      if (!more) break;
      pr = prn; xr = xrn;
    }
  }

  // ---- merge 8 half-waves ----
  if (sl == 0) { mW[hw] = m; lW[hw] = l; }
  *(float4*)&OW[hw][sl * 8]     = make_float4(O[0], O[1], O[2], O[3]);
  *(float4*)&OW[hw][sl * 8 + 4] = make_float4(O[4], O[5], O[6], O[7]);
  __syncthreads();
  float mstar = -INFINITY;
#pragma unroll
  for (int w = 0; w < 8; ++w) mstar = fmaxf(mstar, mW[w]);
  float denom = 0.f, val = 0.f;
#pragma unroll
  for (int w = 0; w < 8; ++w) {
    const float sc = (lW[w] > 0.f) ? __expf(mW[w] - mstar) : 0.f;
    denom += lW[w] * sc;
    val += OW[w][tid] * sc;
  }
  out[(size_t)c * H + tid] = val / fmaxf(denom, 1e-9f);
}

// ---------------- launch ----------------
extern "C" void kernel_launch(void* const* d_in, const int* in_sizes, int n_in,
                              void* d_out, int out_size, void* d_ws, size_t ws_size,
                              hipStream_t stream) {
  const float* news_x    = (const float*)d_in[0];
  const float* company_x = (const float*)d_in[1];
  const float* W_news    = (const float*)d_in[2];
  const float* W_company = (const float*)d_in[3];
  const float* v         = (const float*)d_in[4];
  const int*   src       = (const int*)d_in[5];
  const int*   dst       = (const int*)d_in[6];
  const int N = in_sizes[0] / H;
  const int C = in_sizes[1] / H;
  const int E = in_sizes[5];
  float* out = (float*)d_out;

  char* p = (char*)d_ws;
  ushort* news_projbf    = (ushort*)p; p += (size_t)N * H * sizeof(ushort);
  ushort* news_xbf       = (ushort*)p; p += (size_t)N * H * sizeof(ushort);
  ushort* company_projbf = (ushort*)p; p += (size_t)C * H * sizeof(ushort);
  int*    srcs_sorted    = (int*)p;    p += (size_t)E * sizeof(int);
  ushort* Wn_hi          = (ushort*)p; p += (size_t)H * H * sizeof(ushort);
  ushort* Wn_lo          = (ushort*)p; p += (size_t)H * H * sizeof(ushort);
  ushort* Wc_hi          = (ushort*)p; p += (size_t)H * H * sizeof(ushort);
  ushort* Wc_lo          = (ushort*)p; p += (size_t)H * H * sizeof(ushort);
  int*    counts         = (int*)p;    p += (size_t)C * sizeof(int);
  int*    offsets        = (int*)p;    p += (size_t)(C + 1) * sizeof(int);
  int*    cursor         = (int*)p;    p += (size_t)C * sizeof(int);

  hipMemsetAsync(counts, 0, (size_t)C * sizeof(int), stream);
  prep_kernel<<<512 + (E + 255) / 256, 256, 0, stream>>>(
      W_news, W_company, Wn_hi, Wn_lo, Wc_hi, Wc_lo, dst, counts, E);
  scan_kernel<<<1, 1024, 0, stream>>>(counts, offsets, cursor, C);
  fill_kernel<<<(E + 255) / 256, 256, 0, stream>>>(src, dst, cursor, srcs_sorted, E);

  // 256 blocks x 1024 thr = 16 waves/CU = 4 waves/SIMD (VGPR <= 128).
  // company 157/12 = 13.1 tiles/block, news 3125/244 = 12.8.
  const int GC = 12, GN = 244;
  gemm_persist<<<GC + GN, 1024, 0, stream>>>(
      company_x, Wc_hi, Wc_lo, company_projbf, C, GC,
      news_x, Wn_hi, Wn_lo, news_projbf, news_xbf, N);

  edge_flash_kernel<<<C, 256, 0, stream>>>(news_projbf, company_projbf, v, offsets,
                                           srcs_sorted, news_xbf, out);
}